// Round 7
// baseline (365.326 us; speedup 1.0000x reference)
//
#include <hip/hip_runtime.h>
#include <hip/hip_bf16.h>

typedef __bf16 bf16x8 __attribute__((ext_vector_type(8)));
typedef __bf16 bf16x4 __attribute__((ext_vector_type(4)));
typedef float  f32x4  __attribute__((ext_vector_type(4)));

// ---------------------------------------------------------------------------
// Kernel 1: prep (unchanged — validated)
// ---------------------------------------------------------------------------
__global__ __launch_bounds__(256) void prep_kernel(
    const float* __restrict__ img, const float* __restrict__ ques,
    const float* __restrict__ g_w1, const float* __restrict__ g_b1,
    const float* __restrict__ g_w2, const float* __restrict__ g_w3,
    const float* __restrict__ g_w4,
    float* __restrict__ U, float* __restrict__ V, float* __restrict__ Qb,
    __bf16* __restrict__ W2t, __bf16* __restrict__ W3t, __bf16* __restrict__ W4t) {
  __shared__ float smem[64 * 65];
  const int blk = blockIdx.x;
  const int t = threadIdx.x;

  if (blk < 256) {
    const int n = blk >> 2, obase = (blk & 3) * 16;
    for (int idx = t; idx < 66 * 16; idx += 256) {
      const int c = idx >> 4, o = obase + (idx & 15);
      float v;
      if (c < 64)      v = img[n * 4096 + c * 64 + o];
      else if (c == 64) v = (float)(o >> 3);
      else              v = (float)(o & 7);
      smem[idx] = v;
    }
    __syncthreads();
    float u[16], vv[16];
#pragma unroll
    for (int o = 0; o < 16; ++o) { u[o] = 0.f; vv[o] = 0.f; }
    for (int d = 0; d < 66; ++d) {
      const float wu = g_w1[d * 256 + t];
      const float wv = g_w1[(66 + d) * 256 + t];
#pragma unroll
      for (int o = 0; o < 16; ++o) {
        const float cc = smem[d * 16 + o];
        u[o]  += cc * wu;
        vv[o] += cc * wv;
      }
    }
#pragma unroll
    for (int o = 0; o < 16; ++o) {
      U[(size_t)(n * 64 + obase + o) * 256 + t] = u[o];
      V[(size_t)(n * 64 + obase + o) * 256 + t] = vv[o];
    }
  } else if (blk < 320) {
    const int n = blk - 256;
    smem[t] = ques[n * 256 + t];
    __syncthreads();
    float s = g_b1[t];
    for (int e = 0; e < 256; ++e) s += smem[e] * g_w1[(132 + e) * 256 + t];
    Qb[n * 256 + t] = s;
  } else {
    const int b2 = blk - 320;
    const int wsel = b2 >> 4;
    const int tile = b2 & 15;
    const int r0 = (tile >> 2) * 64, c0 = (tile & 3) * 64;
    const float* W = (wsel == 0) ? g_w2 : (wsel == 1) ? g_w3 : g_w4;
    __bf16* Wt    = (wsel == 0) ? W2t  : (wsel == 1) ? W3t  : W4t;
    const int col = t & 63, rb = (t >> 6) * 16;
#pragma unroll 4
    for (int j = 0; j < 16; ++j)
      smem[(rb + j) * 65 + col] = W[(size_t)(r0 + rb + j) * 256 + c0 + col];
    __syncthreads();
#pragma unroll 4
    for (int j = 0; j < 16; ++j)
      Wt[(size_t)(c0 + rb + j) * 256 + r0 + col] = (__bf16)smem[col * 65 + rb + j];
  }
}

// ---------------------------------------------------------------------------
// Kernel 2: fused g-MLP layers 2..4.
//  ROUND-6 = ROUND-5 K-loop (validated local optimum: M=128, 8 waves x 32c,
//  depth-4 ring, 148 regs spill-free) + per-block-overhead elimination.
//   Diagnosis (rounds 3 vs 5 time model): per-block fixed overhead ~13.5k cyc
//   (barriers + exposed phase-0 latency + epilogue + launch gap) x 8 blocks/CU
//   = ~45 us of round-5's 164 us. K-loop structure left untouched.
//   - PERSISTENT: grid 256 (1 block/CU), 8 units per block; one image n per
//     block (V[n] L1/L2-hot across its 8 ipairs). No inter-block gaps; W ring
//     stays warm across units (LAST layer refills ring with w2 for next unit,
//     making the ring state machine identical every unit).
//   - PING-PONG H (2 x 64 KB): K-loop reads A, stores write B -> BAR1 gone
//     (3 barriers/unit instead of 5; stores don't wait for slowest reader).
//   - phase-0 of unit u+1 runs under layer-4 (B's last readers passed L3's
//     barrier) -> phase-0 global-load latency hidden.
//  H layout: elem(row,c) = (c>>3)*1024 + ((row+(c>>3))&127)*8 + (c&7)
// ---------------------------------------------------------------------------
__device__ __forceinline__ int hidx128(int row, int c) {
  const int kb = c >> 3;
  return kb * 1024 + (((row + kb) & 127) << 3) + (c & 7);
}

// phase 0 for one unit: h1 = relu(U[n,i(row)] + V[n,j(row)] + Qb[n]) -> buf
__device__ __forceinline__ void phase0(const float* __restrict__ U,
                                       const float* __restrict__ V,
                                       const float* __restrict__ Qb,
                                       int nimg, int iobj0, int t,
                                       __bf16* __restrict__ buf) {
  const int c4 = t & 63;          // 4-float col group
  const int rb = t >> 6;          // 0..7 -> rows rb*16 .. rb*16+15
  const int isel = rb >> 2;       // 0 or 1 (static per thread)
  const f32x4 u4 = *(const f32x4*)&U[(size_t)(nimg * 64 + iobj0 + isel) * 256 + c4 * 4];
  const f32x4 q4 = *(const f32x4*)&Qb[(size_t)nimg * 256 + c4 * 4];
  const f32x4 uq = u4 + q4;
#pragma unroll
  for (int jj = 0; jj < 16; ++jj) {
    const int row = rb * 16 + jj;
    const int j = (rb & 3) * 16 + jj;
    const f32x4 v4 = *(const f32x4*)&V[(size_t)(nimg * 64 + j) * 256 + c4 * 4];
    bf16x4 h;
#pragma unroll
    for (int r = 0; r < 4; ++r) h[r] = (__bf16)fmaxf(uq[r] + v4[r], 0.f);
    *(bf16x4*)(&buf[hidx128(row, c4 * 4)]) = h;
  }
}

template <bool LAST>
__device__ __forceinline__ void g_layer(const __bf16* __restrict__ Rb,
                                        __bf16* __restrict__ Wb,
                                        bf16x8 ring[4][2],
                                        const __bf16* __restrict__ wcur,
                                        const __bf16* __restrict__ wnext,
                                        const float* __restrict__ bias_g,
                                        int nq, int q, int r16,
                                        float* __restrict__ pr0,
                                        float* __restrict__ pr1) {
  f32x4 acc[8][2];
  const f32x4 z = {0.f, 0.f, 0.f, 0.f};
#pragma unroll
  for (int m = 0; m < 8; ++m) {
    acc[m][0] = z;
    acc[m][1] = z;
  }

#pragma unroll
  for (int ks = 0; ks < 8; ++ks) {
    const int kb = ks * 4 + q;
    const bf16x8 b0 = ring[ks & 3][0];
    const bf16x8 b1 = ring[ks & 3][1];
    // refill slot: 4 iterations ahead. For LAST, wnext = w2 of the next unit,
    // restoring the exact unit-start ring state (slots d hold w2 K-chunk d).
    if (ks < 4) {
      ring[ks & 3][0] = *(const bf16x8*)(wcur + (ks + 4) * 32);
      ring[ks & 3][1] = *(const bf16x8*)(wcur + 4096 + (ks + 4) * 32);
    } else {
      ring[ks & 3][0] = *(const bf16x8*)(wnext + (ks - 4) * 32);
      ring[ks & 3][1] = *(const bf16x8*)(wnext + 4096 + (ks - 4) * 32);
    }
#pragma unroll
    for (int m = 0; m < 8; ++m) {
      const int row = m * 16 + r16;
      const bf16x8 a = *(const bf16x8*)(&Rb[kb * 1024 + (((row + kb) & 127) << 3)]);
      // swapped operands (verified): acc[m][nt] -> row m*16+r16,
      // cols nq*32 + nt*16 + q*4 + reg
      acc[m][0] = __builtin_amdgcn_mfma_f32_16x16x32_bf16(b0, a, acc[m][0], 0, 0, 0);
      acc[m][1] = __builtin_amdgcn_mfma_f32_16x16x32_bf16(b1, a, acc[m][1], 0, 0, 0);
    }
  }

  f32x4 bv[2];
#pragma unroll
  for (int nt = 0; nt < 2; ++nt)
    bv[nt] = *(const f32x4*)&bias_g[nq * 32 + nt * 16 + q * 4];

  if (!LAST) {
    // ping-pong: Wb != Rb, so stores need no barrier before them
#pragma unroll
    for (int m = 0; m < 8; ++m)
#pragma unroll
      for (int nt = 0; nt < 2; ++nt) {
        const int cb = nq * 32 + nt * 16 + q * 4;
        const f32x4 s = acc[m][nt] + bv[nt];
        bf16x4 h;
#pragma unroll
        for (int r = 0; r < 4; ++r) h[r] = (__bf16)fmaxf(s[r], 0.f);
        *(bf16x4*)(&Wb[hidx128(m * 16 + r16, cb)]) = h;
      }
    __syncthreads();   // stores visible before next layer's reads
  } else {
    // j-sum for both i halves: rows 0-63 (m 0..3) -> i0, 64-127 (m 4..7) -> i1
#pragma unroll
    for (int h = 0; h < 2; ++h) {
#pragma unroll
      for (int nt = 0; nt < 2; ++nt) {
        const int cb = nq * 32 + nt * 16 + q * 4;
        f32x4 s;
#pragma unroll
        for (int r = 0; r < 4; ++r)
          s[r] = fmaxf(acc[h * 4 + 0][nt][r] + bv[nt][r], 0.f)
               + fmaxf(acc[h * 4 + 1][nt][r] + bv[nt][r], 0.f)
               + fmaxf(acc[h * 4 + 2][nt][r] + bv[nt][r], 0.f)
               + fmaxf(acc[h * 4 + 3][nt][r] + bv[nt][r], 0.f);
#pragma unroll
        for (int d = 1; d < 16; d <<= 1) {
#pragma unroll
          for (int r = 0; r < 4; ++r) s[r] += __shfl_xor(s[r], d, 64);
        }
        if (r16 == 0) *(f32x4*)&(h ? pr1 : pr0)[cb] = s;
      }
    }
  }
}

__global__ __launch_bounds__(512, 3) void rn_main(
    const float* __restrict__ U, const float* __restrict__ V,
    const float* __restrict__ Qb,
    const __bf16* __restrict__ W2t, const __bf16* __restrict__ W3t,
    const __bf16* __restrict__ W4t,
    const float* __restrict__ b2, const float* __restrict__ b3,
    const float* __restrict__ b4,
    float* __restrict__ part) {
  __shared__ __align__(16) __bf16 Hs[2 * 32768];   // 128 KB ping-pong
  const int pblk = blockIdx.x;       // 0..255 persistent blocks, 8 units each
  const int t = threadIdx.x;
  const int nq = t >> 6, lane = t & 63;
  const int q = lane >> 4, r16 = lane & 15;

  // per-wave W base pointers (row = output col = nq*32 [+16] + r16, K off q*8)
  const size_t woff = (size_t)(nq * 32 + r16) * 256 + q * 8;
  const __bf16* w2 = W2t + woff;
  const __bf16* w3 = W3t + woff;
  const __bf16* w4 = W4t + woff;

  // ring fill for unit 0 / layer 2 (overlaps phase-0 loads/math)
  bf16x8 ring[4][2];
#pragma unroll
  for (int d = 0; d < 4; ++d) {
    ring[d][0] = *(const bf16x8*)(w2 + d * 32);
    ring[d][1] = *(const bf16x8*)(w2 + 4096 + d * 32);
  }

  // unit u = pblk*8 + u0: nimg = unit>>5, ipair = unit&31 (8 | 32, so one
  // block's 8 units all share one image n -> V[n] stays cache-hot)
  const int unit0 = pblk * 8;

  __bf16* A = Hs;
  __bf16* B = Hs + 32768;

  phase0(U, V, Qb, unit0 >> 5, (unit0 & 31) * 2, t, A);
  __syncthreads();

  for (int u = 0; u < 8; ++u) {
    const int unit = unit0 + u;
    float* pr0 = part + (size_t)unit * 512;
    float* pr1 = pr0 + 256;

    g_layer<false>(A, B, ring, w2, w3, b2, nq, q, r16, pr0, pr1);
    g_layer<false>(B, A, ring, w3, w4, b3, nq, q, r16, pr0, pr1);
    // L4 reads A; ring refilled with w2 (next unit); phase-0(u+1) writes B
    // (B's last readers finished before L3's barrier)
    g_layer<true >(A, B, ring, w4, w2, b4, nq, q, r16, pr0, pr1);
    if (u < 7) {
      const int nu = unit + 1;
      phase0(U, V, Qb, nu >> 5, (nu & 31) * 2, t, B);
    }
    __syncthreads();
    __bf16* tmp = A; A = B; B = tmp;   // next unit's h1 is in B
  }
}

// ---------------------------------------------------------------------------
// Kernel 3: reduce partials -> context, f-MLP (fp32), log_softmax
// ---------------------------------------------------------------------------
__global__ __launch_bounds__(256) void rn_final(
    const float* __restrict__ part,
    const float* __restrict__ f_w1, const float* __restrict__ f_b1,
    const float* __restrict__ f_w2, const float* __restrict__ f_b2,
    const float* __restrict__ f_w3, const float* __restrict__ f_b3,
    float* __restrict__ out) {
  __shared__ float ctx[256], y1[256], y2[256], sc[2];
  const int n = blockIdx.x, t = threadIdx.x;

  float s = 0.f;
  for (int i = 0; i < 64; ++i) s += part[((size_t)n * 64 + i) * 256 + t];
  ctx[t] = s * (1.0f / 4096.0f);
  __syncthreads();

  float a = f_b1[t];
  for (int k = 0; k < 256; ++k) a += ctx[k] * f_w1[k * 256 + t];
  y1[t] = fmaxf(a, 0.f);
  __syncthreads();

  float b = f_b2[t];
  for (int k = 0; k < 256; ++k) b += y1[k] * f_w2[k * 256 + t];
  y2[t] = fmaxf(b, 0.f);
  __syncthreads();

  if (t < 2) {
    float c = f_b3[t];
    for (int k = 0; k < 256; ++k) c += y2[k] * f_w3[k * 2 + t];
    sc[t] = c;
  }
  __syncthreads();

  if (t == 0) {
    const float s0 = sc[0], s1 = sc[1];
    const float mx = fmaxf(s0, s1);
    const float lse = mx + logf(expf(s0 - mx) + expf(s1 - mx));
    out[n * 2 + 0] = s0 - lse;
    out[n * 2 + 1] = s1 - lse;
  }
}

// ---------------------------------------------------------------------------
extern "C" void kernel_launch(void* const* d_in, const int* in_sizes, int n_in,
                              void* d_out, int out_size, void* d_ws, size_t ws_size,
                              hipStream_t stream) {
  const float* img  = (const float*)d_in[0];
  const float* ques = (const float*)d_in[1];
  const float* g_w1 = (const float*)d_in[2];
  const float* g_b1 = (const float*)d_in[3];
  const float* g_w2 = (const float*)d_in[4];
  const float* g_b2 = (const float*)d_in[5];
  const float* g_w3 = (const float*)d_in[6];
  const float* g_b3 = (const float*)d_in[7];
  const float* g_w4 = (const float*)d_in[8];
  const float* g_b4 = (const float*)d_in[9];
  const float* f_w1 = (const float*)d_in[10];
  const float* f_b1 = (const float*)d_in[11];
  const float* f_w2 = (const float*)d_in[12];
  const float* f_b2 = (const float*)d_in[13];
  const float* f_w3 = (const float*)d_in[14];
  const float* f_b3 = (const float*)d_in[15];
  float* out = (float*)d_out;

  char* ws = (char*)d_ws;
  float*  U    = (float*)(ws);                                 // 4 MB
  float*  V    = (float*)(ws + (size_t)4  * 1048576);          // 4 MB
  float*  part = (float*)(ws + (size_t)8  * 1048576);          // 4 MB
  float*  Qb   = (float*)(ws + (size_t)12 * 1048576);          // 64 KB
  __bf16* W2t  = (__bf16*)(ws + (size_t)12 * 1048576 + 65536); // 128 KB each
  __bf16* W3t  = W2t + 65536;
  __bf16* W4t  = W3t + 65536;

  prep_kernel<<<368, 256, 0, stream>>>(img, ques, g_w1, g_b1, g_w2, g_w3, g_w4,
                                       U, V, Qb, W2t, W3t, W4t);
  rn_main<<<256, 512, 0, stream>>>(U, V, Qb, W2t, W3t, W4t, g_b2, g_b3, g_b4, part);
  rn_final<<<64, 256, 0, stream>>>(part, f_w1, f_b1, f_w2, f_b2, f_w3, f_b3, out);
}

// Round 8
// 240.568 us; speedup vs baseline: 1.5186x; 1.5186x over previous
//
#include <hip/hip_runtime.h>
#include <hip/hip_bf16.h>

typedef __bf16 bf16x8 __attribute__((ext_vector_type(8)));
typedef __bf16 bf16x4 __attribute__((ext_vector_type(4)));
typedef float  f32x4  __attribute__((ext_vector_type(4)));

// ---------------------------------------------------------------------------
// Kernel 1: prep (unchanged — validated)
// ---------------------------------------------------------------------------
__global__ __launch_bounds__(256) void prep_kernel(
    const float* __restrict__ img, const float* __restrict__ ques,
    const float* __restrict__ g_w1, const float* __restrict__ g_b1,
    const float* __restrict__ g_w2, const float* __restrict__ g_w3,
    const float* __restrict__ g_w4,
    float* __restrict__ U, float* __restrict__ V, float* __restrict__ Qb,
    __bf16* __restrict__ W2t, __bf16* __restrict__ W3t, __bf16* __restrict__ W4t) {
  __shared__ float smem[64 * 65];
  const int blk = blockIdx.x;
  const int t = threadIdx.x;

  if (blk < 256) {
    const int n = blk >> 2, obase = (blk & 3) * 16;
    for (int idx = t; idx < 66 * 16; idx += 256) {
      const int c = idx >> 4, o = obase + (idx & 15);
      float v;
      if (c < 64)      v = img[n * 4096 + c * 64 + o];
      else if (c == 64) v = (float)(o >> 3);
      else              v = (float)(o & 7);
      smem[idx] = v;
    }
    __syncthreads();
    float u[16], vv[16];
#pragma unroll
    for (int o = 0; o < 16; ++o) { u[o] = 0.f; vv[o] = 0.f; }
    for (int d = 0; d < 66; ++d) {
      const float wu = g_w1[d * 256 + t];
      const float wv = g_w1[(66 + d) * 256 + t];
#pragma unroll
      for (int o = 0; o < 16; ++o) {
        const float cc = smem[d * 16 + o];
        u[o]  += cc * wu;
        vv[o] += cc * wv;
      }
    }
#pragma unroll
    for (int o = 0; o < 16; ++o) {
      U[(size_t)(n * 64 + obase + o) * 256 + t] = u[o];
      V[(size_t)(n * 64 + obase + o) * 256 + t] = vv[o];
    }
  } else if (blk < 320) {
    const int n = blk - 256;
    smem[t] = ques[n * 256 + t];
    __syncthreads();
    float s = g_b1[t];
    for (int e = 0; e < 256; ++e) s += smem[e] * g_w1[(132 + e) * 256 + t];
    Qb[n * 256 + t] = s;
  } else {
    const int b2 = blk - 320;
    const int wsel = b2 >> 4;
    const int tile = b2 & 15;
    const int r0 = (tile >> 2) * 64, c0 = (tile & 3) * 64;
    const float* W = (wsel == 0) ? g_w2 : (wsel == 1) ? g_w3 : g_w4;
    __bf16* Wt    = (wsel == 0) ? W2t  : (wsel == 1) ? W3t  : W4t;
    const int col = t & 63, rb = (t >> 6) * 16;
#pragma unroll 4
    for (int j = 0; j < 16; ++j)
      smem[(rb + j) * 65 + col] = W[(size_t)(r0 + rb + j) * 256 + c0 + col];
    __syncthreads();
#pragma unroll 4
    for (int j = 0; j < 16; ++j)
      Wt[(size_t)(c0 + rb + j) * 256 + r0 + col] = (__bf16)smem[col * 65 + rb + j];
  }
}

// ---------------------------------------------------------------------------
// Kernel 2: fused g-MLP layers 2..4.
//  ROUND-7: best-measured structure (R3 bench: M=128, grid 2048, in-place H,
//  2 blocks/CU) with the register budget FINALLY fit to the 128-reg cap.
//   Seven-round model: perf ~ (resident waves) x (MFMA per barrier window),
//   spill = second-order tax. Frontier = M=128 @ 2 blocks/CU, zero spill.
//   Demand with depth-4 ring was ~148 regs -> the 20-reg overshoot IS the
//   ring (32 VGPR). Fix: depth-2 b double-buffer (16 VGPR, lead = 1 K-step).
//   acc 64 + bb 16 + a 4 + temps ~25 <= 128 -> fits (512,4) spill-free;
//   the shorter prefetch lead is covered by the restored 2-blocks/CU TLP.
//   M=128 per block (2 i-objects), 512 thr / 8 waves, wave owns 128r x 32c
//   (zero W duplication). SINGLE 64 KB in-place H; BAR1 post-K-loop.
//  H layout: elem(row,c) = (c>>3)*1024 + ((row+(c>>3))&127)*8 + (c&7)
// ---------------------------------------------------------------------------
__device__ __forceinline__ int hidx128(int row, int c) {
  const int kb = c >> 3;
  return kb * 1024 + (((row + kb) & 127) << 3) + (c & 7);
}

template <bool LAST>
__device__ __forceinline__ void g_layer(__bf16* Hs,
                                        bf16x8 bb[2][2],
                                        const __bf16* __restrict__ wcur,
                                        const __bf16* __restrict__ wnext,
                                        const float* __restrict__ bias_g,
                                        int nq, int q, int r16,
                                        float* __restrict__ pr0,
                                        float* __restrict__ pr1) {
  f32x4 acc[8][2];
  const f32x4 z = {0.f, 0.f, 0.f, 0.f};
#pragma unroll
  for (int m = 0; m < 8; ++m) {
    acc[m][0] = z;
    acc[m][1] = z;
  }

#pragma unroll
  for (int ks = 0; ks < 8; ++ks) {
    const int kb = ks * 4 + q;
    const bf16x8 b0 = bb[ks & 1][0];
    const bf16x8 b1 = bb[ks & 1][1];
    // refill other slot: 1 K-step ahead; at ks=7 load next layer's ks=0
    // (slot parity consistent across layers since 8 is even)
    if (ks < 7) {
      bb[(ks + 1) & 1][0] = *(const bf16x8*)(wcur + (ks + 1) * 32);
      bb[(ks + 1) & 1][1] = *(const bf16x8*)(wcur + 4096 + (ks + 1) * 32);
    } else if (!LAST) {
      bb[0][0] = *(const bf16x8*)(wnext);
      bb[0][1] = *(const bf16x8*)(wnext + 4096);
    }
#pragma unroll
    for (int m = 0; m < 8; ++m) {
      const int row = m * 16 + r16;
      const bf16x8 a = *(const bf16x8*)(&Hs[kb * 1024 + (((row + kb) & 127) << 3)]);
      // swapped operands (verified): acc[m][nt] -> row m*16+r16,
      // cols nq*32 + nt*16 + q*4 + reg
      acc[m][0] = __builtin_amdgcn_mfma_f32_16x16x32_bf16(b0, a, acc[m][0], 0, 0, 0);
      acc[m][1] = __builtin_amdgcn_mfma_f32_16x16x32_bf16(b1, a, acc[m][1], 0, 0, 0);
    }
  }

  f32x4 bv[2];
#pragma unroll
  for (int nt = 0; nt < 2; ++nt)
    bv[nt] = *(const f32x4*)&bias_g[nq * 32 + nt * 16 + q * 4];

  if (!LAST) {
    __syncthreads();   // BAR1: all waves finished reading Hs -> in-place safe
#pragma unroll
    for (int m = 0; m < 8; ++m)
#pragma unroll
      for (int nt = 0; nt < 2; ++nt) {
        const int cb = nq * 32 + nt * 16 + q * 4;
        const f32x4 s = acc[m][nt] + bv[nt];
        bf16x4 h;
#pragma unroll
        for (int r = 0; r < 4; ++r) h[r] = (__bf16)fmaxf(s[r], 0.f);
        *(bf16x4*)(&Hs[hidx128(m * 16 + r16, cb)]) = h;
      }
    __syncthreads();   // BAR2: stores visible before next layer's reads
  } else {
    // j-sum for both i halves: rows 0-63 (m 0..3) -> i0, 64-127 (m 4..7) -> i1
#pragma unroll
    for (int h = 0; h < 2; ++h) {
#pragma unroll
      for (int nt = 0; nt < 2; ++nt) {
        const int cb = nq * 32 + nt * 16 + q * 4;
        f32x4 s;
#pragma unroll
        for (int r = 0; r < 4; ++r)
          s[r] = fmaxf(acc[h * 4 + 0][nt][r] + bv[nt][r], 0.f)
               + fmaxf(acc[h * 4 + 1][nt][r] + bv[nt][r], 0.f)
               + fmaxf(acc[h * 4 + 2][nt][r] + bv[nt][r], 0.f)
               + fmaxf(acc[h * 4 + 3][nt][r] + bv[nt][r], 0.f);
#pragma unroll
        for (int d = 1; d < 16; d <<= 1) {
#pragma unroll
          for (int r = 0; r < 4; ++r) s[r] += __shfl_xor(s[r], d, 64);
        }
        if (r16 == 0) *(f32x4*)&(h ? pr1 : pr0)[cb] = s;
      }
    }
  }
}

__global__ __launch_bounds__(512, 4) void rn_main(
    const float* __restrict__ U, const float* __restrict__ V,
    const float* __restrict__ Qb,
    const __bf16* __restrict__ W2t, const __bf16* __restrict__ W3t,
    const __bf16* __restrict__ W4t,
    const float* __restrict__ b2, const float* __restrict__ b3,
    const float* __restrict__ b4,
    float* __restrict__ part) {
  __shared__ __align__(16) __bf16 Hs[32768];   // 64 KB, in-place
  const int blk = blockIdx.x;
  const int nimg = blk >> 5, ipair = blk & 31;
  const int iobj0 = ipair * 2;
  const int t = threadIdx.x;
  const int nq = t >> 6, lane = t & 63;
  const int q = lane >> 4, r16 = lane & 15;

  // per-wave W base pointers (row = output col = nq*32 [+16] + r16, K off q*8)
  const size_t woff = (size_t)(nq * 32 + r16) * 256 + q * 8;
  const __bf16* w2 = W2t + woff;
  const __bf16* w3 = W3t + woff;
  const __bf16* w4 = W4t + woff;

  // b double-buffer: preload layer-2 ks=0 (overlaps phase-0 loads/math)
  bf16x8 bb[2][2];
  bb[0][0] = *(const bf16x8*)(w2);
  bb[0][1] = *(const bf16x8*)(w2 + 4096);

  // phase 0: rows 0-63 -> i0, rows 64-127 -> i1
  // h1[row][:] = relu(U[n, i(row), :] + V[n, j(row), :] + Qb[n, :])
  {
    const int c4 = t & 63;          // 4-float col group
    const int rb = t >> 6;          // 0..7 -> rows rb*16 .. rb*16+15
    const int isel = rb >> 2;       // 0 or 1 (static per thread)
    const f32x4 u4 = *(const f32x4*)&U[(size_t)(nimg * 64 + iobj0 + isel) * 256 + c4 * 4];
    const f32x4 q4 = *(const f32x4*)&Qb[(size_t)nimg * 256 + c4 * 4];
    const f32x4 uq = u4 + q4;
#pragma unroll
    for (int jj = 0; jj < 16; ++jj) {
      const int row = rb * 16 + jj;
      const int j = (rb & 3) * 16 + jj;
      const f32x4 v4 = *(const f32x4*)&V[(size_t)(nimg * 64 + j) * 256 + c4 * 4];
      bf16x4 h;
#pragma unroll
      for (int r = 0; r < 4; ++r) h[r] = (__bf16)fmaxf(uq[r] + v4[r], 0.f);
      *(bf16x4*)(&Hs[hidx128(row, c4 * 4)]) = h;
    }
  }
  __syncthreads();

  // part rows: global i-row index = nimg*64 + iobj0 (+1) = blk*2 (+1)
  float* pr0 = part + (size_t)blk * 512;
  float* pr1 = pr0 + 256;

  g_layer<false>(Hs, bb, w2, w3, b2, nq, q, r16, pr0, pr1);
  g_layer<false>(Hs, bb, w3, w4, b3, nq, q, r16, pr0, pr1);
  g_layer<true >(Hs, bb, w4, w4, b4, nq, q, r16, pr0, pr1);
}

// ---------------------------------------------------------------------------
// Kernel 3: reduce partials -> context, f-MLP (fp32), log_softmax
// ---------------------------------------------------------------------------
__global__ __launch_bounds__(256) void rn_final(
    const float* __restrict__ part,
    const float* __restrict__ f_w1, const float* __restrict__ f_b1,
    const float* __restrict__ f_w2, const float* __restrict__ f_b2,
    const float* __restrict__ f_w3, const float* __restrict__ f_b3,
    float* __restrict__ out) {
  __shared__ float ctx[256], y1[256], y2[256], sc[2];
  const int n = blockIdx.x, t = threadIdx.x;

  float s = 0.f;
  for (int i = 0; i < 64; ++i) s += part[((size_t)n * 64 + i) * 256 + t];
  ctx[t] = s * (1.0f / 4096.0f);
  __syncthreads();

  float a = f_b1[t];
  for (int k = 0; k < 256; ++k) a += ctx[k] * f_w1[k * 256 + t];
  y1[t] = fmaxf(a, 0.f);
  __syncthreads();

  float b = f_b2[t];
  for (int k = 0; k < 256; ++k) b += y1[k] * f_w2[k * 256 + t];
  y2[t] = fmaxf(b, 0.f);
  __syncthreads();

  if (t < 2) {
    float c = f_b3[t];
    for (int k = 0; k < 256; ++k) c += y2[k] * f_w3[k * 2 + t];
    sc[t] = c;
  }
  __syncthreads();

  if (t == 0) {
    const float s0 = sc[0], s1 = sc[1];
    const float mx = fmaxf(s0, s1);
    const float lse = mx + logf(expf(s0 - mx) + expf(s1 - mx));
    out[n * 2 + 0] = s0 - lse;
    out[n * 2 + 1] = s1 - lse;
  }
}

// ---------------------------------------------------------------------------
extern "C" void kernel_launch(void* const* d_in, const int* in_sizes, int n_in,
                              void* d_out, int out_size, void* d_ws, size_t ws_size,
                              hipStream_t stream) {
  const float* img  = (const float*)d_in[0];
  const float* ques = (const float*)d_in[1];
  const float* g_w1 = (const float*)d_in[2];
  const float* g_b1 = (const float*)d_in[3];
  const float* g_w2 = (const float*)d_in[4];
  const float* g_b2 = (const float*)d_in[5];
  const float* g_w3 = (const float*)d_in[6];
  const float* g_b3 = (const float*)d_in[7];
  const float* g_w4 = (const float*)d_in[8];
  const float* g_b4 = (const float*)d_in[9];
  const float* f_w1 = (const float*)d_in[10];
  const float* f_b1 = (const float*)d_in[11];
  const float* f_w2 = (const float*)d_in[12];
  const float* f_b2 = (const float*)d_in[13];
  const float* f_w3 = (const float*)d_in[14];
  const float* f_b3 = (const float*)d_in[15];
  float* out = (float*)d_out;

  char* ws = (char*)d_ws;
  float*  U    = (float*)(ws);                                 // 4 MB
  float*  V    = (float*)(ws + (size_t)4  * 1048576);          // 4 MB
  float*  part = (float*)(ws + (size_t)8  * 1048576);          // 4 MB
  float*  Qb   = (float*)(ws + (size_t)12 * 1048576);          // 64 KB
  __bf16* W2t  = (__bf16*)(ws + (size_t)12 * 1048576 + 65536); // 128 KB each
  __bf16* W3t  = W2t + 65536;
  __bf16* W4t  = W3t + 65536;

  prep_kernel<<<368, 256, 0, stream>>>(img, ques, g_w1, g_b1, g_w2, g_w3, g_w4,
                                       U, V, Qb, W2t, W3t, W4t);
  rn_main<<<2048, 512, 0, stream>>>(U, V, Qb, W2t, W3t, W4t, g_b2, g_b3, g_b4, part);
  rn_final<<<64, 256, 0, stream>>>(part, f_w1, f_b1, f_w2, f_b2, f_w3, f_b3, out);
}

// Round 9
// 232.624 us; speedup vs baseline: 1.5705x; 1.0342x over previous
//
#include <hip/hip_runtime.h>
#include <hip/hip_bf16.h>

typedef __bf16 bf16x8 __attribute__((ext_vector_type(8)));
typedef __bf16 bf16x4 __attribute__((ext_vector_type(4)));
typedef float  f32x4  __attribute__((ext_vector_type(4)));

// ---------------------------------------------------------------------------
// Kernel 1: prep (unchanged — validated)
// ---------------------------------------------------------------------------
__global__ __launch_bounds__(256) void prep_kernel(
    const float* __restrict__ img, const float* __restrict__ ques,
    const float* __restrict__ g_w1, const float* __restrict__ g_b1,
    const float* __restrict__ g_w2, const float* __restrict__ g_w3,
    const float* __restrict__ g_w4,
    float* __restrict__ U, float* __restrict__ V, float* __restrict__ Qb,
    __bf16* __restrict__ W2t, __bf16* __restrict__ W3t, __bf16* __restrict__ W4t) {
  __shared__ float smem[64 * 65];
  const int blk = blockIdx.x;
  const int t = threadIdx.x;

  if (blk < 256) {
    const int n = blk >> 2, obase = (blk & 3) * 16;
    for (int idx = t; idx < 66 * 16; idx += 256) {
      const int c = idx >> 4, o = obase + (idx & 15);
      float v;
      if (c < 64)      v = img[n * 4096 + c * 64 + o];
      else if (c == 64) v = (float)(o >> 3);
      else              v = (float)(o & 7);
      smem[idx] = v;
    }
    __syncthreads();
    float u[16], vv[16];
#pragma unroll
    for (int o = 0; o < 16; ++o) { u[o] = 0.f; vv[o] = 0.f; }
    for (int d = 0; d < 66; ++d) {
      const float wu = g_w1[d * 256 + t];
      const float wv = g_w1[(66 + d) * 256 + t];
#pragma unroll
      for (int o = 0; o < 16; ++o) {
        const float cc = smem[d * 16 + o];
        u[o]  += cc * wu;
        vv[o] += cc * wv;
      }
    }
#pragma unroll
    for (int o = 0; o < 16; ++o) {
      U[(size_t)(n * 64 + obase + o) * 256 + t] = u[o];
      V[(size_t)(n * 64 + obase + o) * 256 + t] = vv[o];
    }
  } else if (blk < 320) {
    const int n = blk - 256;
    smem[t] = ques[n * 256 + t];
    __syncthreads();
    float s = g_b1[t];
    for (int e = 0; e < 256; ++e) s += smem[e] * g_w1[(132 + e) * 256 + t];
    Qb[n * 256 + t] = s;
  } else {
    const int b2 = blk - 320;
    const int wsel = b2 >> 4;
    const int tile = b2 & 15;
    const int r0 = (tile >> 2) * 64, c0 = (tile & 3) * 64;
    const float* W = (wsel == 0) ? g_w2 : (wsel == 1) ? g_w3 : g_w4;
    __bf16* Wt    = (wsel == 0) ? W2t  : (wsel == 1) ? W3t  : W4t;
    const int col = t & 63, rb = (t >> 6) * 16;
#pragma unroll 4
    for (int j = 0; j < 16; ++j)
      smem[(rb + j) * 65 + col] = W[(size_t)(r0 + rb + j) * 256 + c0 + col];
    __syncthreads();
#pragma unroll 4
    for (int j = 0; j < 16; ++j)
      Wt[(size_t)(c0 + rb + j) * 256 + r0 + col] = (__bf16)smem[col * 65 + rb + j];
  }
}

// ---------------------------------------------------------------------------
// Kernel 2: fused g-MLP layers 2..4.
//  ROUND-8 = ROUND-7 + bias-in-accumulator-init (frees ~8 VGPR).
//   R7 post-mortem: VGPR_Count pinned at 64 (= 128 unified cap - 64 AGPR) and
//   88 MB scratch WRITE -> still spilling ~4-8 regs. R5 measured 84 arch
//   demand with ring-4(32); bb-2(16) => ~68, i.e. 4 over the cap.
//   FIX: init acc[m][nt] = bias[nt] instead of 0 (C/D col = nq*32+nt*16+q*4+r
//   depends only on (nt,r), constant over m -> mathematically identical to
//   adding bv in the epilogue). bv is dead before the K-loop -> peak demand
//   ~60 <= 64 arch -> spill-free at (512,4) with 2 blocks/CU.
//   Everything else byte-identical to R7: M=128 (2 i-objects), 512 thr /
//   8 waves, wave owns 128r x 32c, depth-2 b double-buffer, in-place 64 KB H,
//   BAR1 post-K-loop + BAR2 publish, grid 2048.
//  H layout: elem(row,c) = (c>>3)*1024 + ((row+(c>>3))&127)*8 + (c&7)
// ---------------------------------------------------------------------------
__device__ __forceinline__ int hidx128(int row, int c) {
  const int kb = c >> 3;
  return kb * 1024 + (((row + kb) & 127) << 3) + (c & 7);
}

template <bool LAST>
__device__ __forceinline__ void g_layer(__bf16* Hs,
                                        bf16x8 bb[2][2],
                                        const __bf16* __restrict__ wcur,
                                        const __bf16* __restrict__ wnext,
                                        const float* __restrict__ bias_g,
                                        int nq, int q, int r16,
                                        float* __restrict__ pr0,
                                        float* __restrict__ pr1) {
  f32x4 acc[8][2];
  {
    // bias folded into acc init (col bias constant over m); bv dead after this
    const f32x4 bv0 = *(const f32x4*)&bias_g[nq * 32 + 0 * 16 + q * 4];
    const f32x4 bv1 = *(const f32x4*)&bias_g[nq * 32 + 1 * 16 + q * 4];
#pragma unroll
    for (int m = 0; m < 8; ++m) {
      acc[m][0] = bv0;
      acc[m][1] = bv1;
    }
  }

#pragma unroll
  for (int ks = 0; ks < 8; ++ks) {
    const int kb = ks * 4 + q;
    const bf16x8 b0 = bb[ks & 1][0];
    const bf16x8 b1 = bb[ks & 1][1];
    // refill other slot: 1 K-step ahead; at ks=7 load next layer's ks=0
    // (slot parity consistent across layers since 8 is even)
    if (ks < 7) {
      bb[(ks + 1) & 1][0] = *(const bf16x8*)(wcur + (ks + 1) * 32);
      bb[(ks + 1) & 1][1] = *(const bf16x8*)(wcur + 4096 + (ks + 1) * 32);
    } else if (!LAST) {
      bb[0][0] = *(const bf16x8*)(wnext);
      bb[0][1] = *(const bf16x8*)(wnext + 4096);
    }
#pragma unroll
    for (int m = 0; m < 8; ++m) {
      const int row = m * 16 + r16;
      const bf16x8 a = *(const bf16x8*)(&Hs[kb * 1024 + (((row + kb) & 127) << 3)]);
      // swapped operands (verified): acc[m][nt] -> row m*16+r16,
      // cols nq*32 + nt*16 + q*4 + reg
      acc[m][0] = __builtin_amdgcn_mfma_f32_16x16x32_bf16(b0, a, acc[m][0], 0, 0, 0);
      acc[m][1] = __builtin_amdgcn_mfma_f32_16x16x32_bf16(b1, a, acc[m][1], 0, 0, 0);
    }
  }

  if (!LAST) {
    __syncthreads();   // BAR1: all waves finished reading Hs -> in-place safe
#pragma unroll
    for (int m = 0; m < 8; ++m)
#pragma unroll
      for (int nt = 0; nt < 2; ++nt) {
        const int cb = nq * 32 + nt * 16 + q * 4;
        bf16x4 h;
#pragma unroll
        for (int r = 0; r < 4; ++r) h[r] = (__bf16)fmaxf(acc[m][nt][r], 0.f);
        *(bf16x4*)(&Hs[hidx128(m * 16 + r16, cb)]) = h;
      }
    __syncthreads();   // BAR2: stores visible before next layer's reads
  } else {
    // j-sum for both i halves: rows 0-63 (m 0..3) -> i0, 64-127 (m 4..7) -> i1
#pragma unroll
    for (int h = 0; h < 2; ++h) {
#pragma unroll
      for (int nt = 0; nt < 2; ++nt) {
        const int cb = nq * 32 + nt * 16 + q * 4;
        f32x4 s;
#pragma unroll
        for (int r = 0; r < 4; ++r)
          s[r] = fmaxf(acc[h * 4 + 0][nt][r], 0.f)
               + fmaxf(acc[h * 4 + 1][nt][r], 0.f)
               + fmaxf(acc[h * 4 + 2][nt][r], 0.f)
               + fmaxf(acc[h * 4 + 3][nt][r], 0.f);
#pragma unroll
        for (int d = 1; d < 16; d <<= 1) {
#pragma unroll
          for (int r = 0; r < 4; ++r) s[r] += __shfl_xor(s[r], d, 64);
        }
        if (r16 == 0) *(f32x4*)&(h ? pr1 : pr0)[cb] = s;
      }
    }
  }
}

__global__ __launch_bounds__(512, 4) void rn_main(
    const float* __restrict__ U, const float* __restrict__ V,
    const float* __restrict__ Qb,
    const __bf16* __restrict__ W2t, const __bf16* __restrict__ W3t,
    const __bf16* __restrict__ W4t,
    const float* __restrict__ b2, const float* __restrict__ b3,
    const float* __restrict__ b4,
    float* __restrict__ part) {
  __shared__ __align__(16) __bf16 Hs[32768];   // 64 KB, in-place
  const int blk = blockIdx.x;
  const int nimg = blk >> 5, ipair = blk & 31;
  const int iobj0 = ipair * 2;
  const int t = threadIdx.x;
  const int nq = t >> 6, lane = t & 63;
  const int q = lane >> 4, r16 = lane & 15;

  // per-wave W base pointers (row = output col = nq*32 [+16] + r16, K off q*8)
  const size_t woff = (size_t)(nq * 32 + r16) * 256 + q * 8;
  const __bf16* w2 = W2t + woff;
  const __bf16* w3 = W3t + woff;
  const __bf16* w4 = W4t + woff;

  // b double-buffer: preload layer-2 ks=0 (overlaps phase-0 loads/math)
  bf16x8 bb[2][2];
  bb[0][0] = *(const bf16x8*)(w2);
  bb[0][1] = *(const bf16x8*)(w2 + 4096);

  // phase 0: rows 0-63 -> i0, rows 64-127 -> i1
  // h1[row][:] = relu(U[n, i(row), :] + V[n, j(row), :] + Qb[n, :])
  {
    const int c4 = t & 63;          // 4-float col group
    const int rb = t >> 6;          // 0..7 -> rows rb*16 .. rb*16+15
    const int isel = rb >> 2;       // 0 or 1 (static per thread)
    const f32x4 u4 = *(const f32x4*)&U[(size_t)(nimg * 64 + iobj0 + isel) * 256 + c4 * 4];
    const f32x4 q4 = *(const f32x4*)&Qb[(size_t)nimg * 256 + c4 * 4];
    const f32x4 uq = u4 + q4;
#pragma unroll
    for (int jj = 0; jj < 16; ++jj) {
      const int row = rb * 16 + jj;
      const int j = (rb & 3) * 16 + jj;
      const f32x4 v4 = *(const f32x4*)&V[(size_t)(nimg * 64 + j) * 256 + c4 * 4];
      bf16x4 h;
#pragma unroll
      for (int r = 0; r < 4; ++r) h[r] = (__bf16)fmaxf(uq[r] + v4[r], 0.f);
      *(bf16x4*)(&Hs[hidx128(row, c4 * 4)]) = h;
    }
  }
  __syncthreads();

  // part rows: global i-row index = nimg*64 + iobj0 (+1) = blk*2 (+1)
  float* pr0 = part + (size_t)blk * 512;
  float* pr1 = pr0 + 256;

  g_layer<false>(Hs, bb, w2, w3, b2, nq, q, r16, pr0, pr1);
  g_layer<false>(Hs, bb, w3, w4, b3, nq, q, r16, pr0, pr1);
  g_layer<true >(Hs, bb, w4, w4, b4, nq, q, r16, pr0, pr1);
}

// ---------------------------------------------------------------------------
// Kernel 3: reduce partials -> context, f-MLP (fp32), log_softmax
// ---------------------------------------------------------------------------
__global__ __launch_bounds__(256) void rn_final(
    const float* __restrict__ part,
    const float* __restrict__ f_w1, const float* __restrict__ f_b1,
    const float* __restrict__ f_w2, const float* __restrict__ f_b2,
    const float* __restrict__ f_w3, const float* __restrict__ f_b3,
    float* __restrict__ out) {
  __shared__ float ctx[256], y1[256], y2[256], sc[2];
  const int n = blockIdx.x, t = threadIdx.x;

  float s = 0.f;
  for (int i = 0; i < 64; ++i) s += part[((size_t)n * 64 + i) * 256 + t];
  ctx[t] = s * (1.0f / 4096.0f);
  __syncthreads();

  float a = f_b1[t];
  for (int k = 0; k < 256; ++k) a += ctx[k] * f_w1[k * 256 + t];
  y1[t] = fmaxf(a, 0.f);
  __syncthreads();

  float b = f_b2[t];
  for (int k = 0; k < 256; ++k) b += y1[k] * f_w2[k * 256 + t];
  y2[t] = fmaxf(b, 0.f);
  __syncthreads();

  if (t < 2) {
    float c = f_b3[t];
    for (int k = 0; k < 256; ++k) c += y2[k] * f_w3[k * 2 + t];
    sc[t] = c;
  }
  __syncthreads();

  if (t == 0) {
    const float s0 = sc[0], s1 = sc[1];
    const float mx = fmaxf(s0, s1);
    const float lse = mx + logf(expf(s0 - mx) + expf(s1 - mx));
    out[n * 2 + 0] = s0 - lse;
    out[n * 2 + 1] = s1 - lse;
  }
}

// ---------------------------------------------------------------------------
extern "C" void kernel_launch(void* const* d_in, const int* in_sizes, int n_in,
                              void* d_out, int out_size, void* d_ws, size_t ws_size,
                              hipStream_t stream) {
  const float* img  = (const float*)d_in[0];
  const float* ques = (const float*)d_in[1];
  const float* g_w1 = (const float*)d_in[2];
  const float* g_b1 = (const float*)d_in[3];
  const float* g_w2 = (const float*)d_in[4];
  const float* g_b2 = (const float*)d_in[5];
  const float* g_w3 = (const float*)d_in[6];
  const float* g_b3 = (const float*)d_in[7];
  const float* g_w4 = (const float*)d_in[8];
  const float* g_b4 = (const float*)d_in[9];
  const float* f_w1 = (const float*)d_in[10];
  const float* f_b1 = (const float*)d_in[11];
  const float* f_w2 = (const float*)d_in[12];
  const float* f_b2 = (const float*)d_in[13];
  const float* f_w3 = (const float*)d_in[14];
  const float* f_b3 = (const float*)d_in[15];
  float* out = (float*)d_out;

  char* ws = (char*)d_ws;
  float*  U    = (float*)(ws);                                 // 4 MB
  float*  V    = (float*)(ws + (size_t)4  * 1048576);          // 4 MB
  float*  part = (float*)(ws + (size_t)8  * 1048576);          // 4 MB
  float*  Qb   = (float*)(ws + (size_t)12 * 1048576);          // 64 KB
  __bf16* W2t  = (__bf16*)(ws + (size_t)12 * 1048576 + 65536); // 128 KB each
  __bf16* W3t  = W2t + 65536;
  __bf16* W4t  = W3t + 65536;

  prep_kernel<<<368, 256, 0, stream>>>(img, ques, g_w1, g_b1, g_w2, g_w3, g_w4,
                                       U, V, Qb, W2t, W3t, W4t);
  rn_main<<<2048, 512, 0, stream>>>(U, V, Qb, W2t, W3t, W4t, g_b2, g_b3, g_b4, part);
  rn_final<<<64, 256, 0, stream>>>(part, f_w1, f_b1, f_w2, f_b2, f_w3, f_b3, out);
}

// Round 11
// 228.591 us; speedup vs baseline: 1.5982x; 1.0176x over previous
//
#include <hip/hip_runtime.h>
#include <hip/hip_bf16.h>

typedef __bf16 bf16x8 __attribute__((ext_vector_type(8)));
typedef __bf16 bf16x4 __attribute__((ext_vector_type(4)));
typedef float  f32x4  __attribute__((ext_vector_type(4)));

// ---------------------------------------------------------------------------
// Kernel 1: prep. ROUND-9: U/V branch split 256->512 blocks (8 objects each)
// + d-loop unroll 2: halves the per-block dependent-load chain and doubles
// block parallelism (was 1 block/CU, rolled 66-iter loop, latency-exposed).
// Qb / W-transpose branches logic unchanged (block indices shifted).
// ---------------------------------------------------------------------------
__global__ __launch_bounds__(256) void prep_kernel(
    const float* __restrict__ img, const float* __restrict__ ques,
    const float* __restrict__ g_w1, const float* __restrict__ g_b1,
    const float* __restrict__ g_w2, const float* __restrict__ g_w3,
    const float* __restrict__ g_w4,
    float* __restrict__ U, float* __restrict__ V, float* __restrict__ Qb,
    __bf16* __restrict__ W2t, __bf16* __restrict__ W3t, __bf16* __restrict__ W4t) {
  __shared__ float smem[64 * 65];
  const int blk = blockIdx.x;
  const int t = threadIdx.x;

  if (blk < 512) {
    const int n = blk >> 3, obase = (blk & 7) * 8;
    for (int idx = t; idx < 66 * 8; idx += 256) {
      const int c = idx >> 3, o = obase + (idx & 7);
      float v;
      if (c < 64)      v = img[n * 4096 + c * 64 + o];
      else if (c == 64) v = (float)(o >> 3);
      else              v = (float)(o & 7);
      smem[idx] = v;
    }
    __syncthreads();
    float u[8], vv[8];
#pragma unroll
    for (int o = 0; o < 8; ++o) { u[o] = 0.f; vv[o] = 0.f; }
#pragma unroll 2
    for (int d = 0; d < 66; ++d) {
      const float wu = g_w1[d * 256 + t];
      const float wv = g_w1[(66 + d) * 256 + t];
#pragma unroll
      for (int o = 0; o < 8; ++o) {
        const float cc = smem[d * 8 + o];
        u[o]  += cc * wu;
        vv[o] += cc * wv;
      }
    }
#pragma unroll
    for (int o = 0; o < 8; ++o) {
      U[(size_t)(n * 64 + obase + o) * 256 + t] = u[o];
      V[(size_t)(n * 64 + obase + o) * 256 + t] = vv[o];
    }
  } else if (blk < 576) {
    const int n = blk - 512;
    smem[t] = ques[n * 256 + t];
    __syncthreads();
    float s = g_b1[t];
    for (int e = 0; e < 256; ++e) s += smem[e] * g_w1[(132 + e) * 256 + t];
    Qb[n * 256 + t] = s;
  } else {
    const int b2 = blk - 576;
    const int wsel = b2 >> 4;
    const int tile = b2 & 15;
    const int r0 = (tile >> 2) * 64, c0 = (tile & 3) * 64;
    const float* W = (wsel == 0) ? g_w2 : (wsel == 1) ? g_w3 : g_w4;
    __bf16* Wt    = (wsel == 0) ? W2t  : (wsel == 1) ? W3t  : W4t;
    const int col = t & 63, rb = (t >> 6) * 16;
#pragma unroll 4
    for (int j = 0; j < 16; ++j)
      smem[(rb + j) * 65 + col] = W[(size_t)(r0 + rb + j) * 256 + c0 + col];
    __syncthreads();
#pragma unroll 4
    for (int j = 0; j < 16; ++j)
      Wt[(size_t)(c0 + rb + j) * 256 + r0 + col] = (__bf16)smem[col * 65 + rb + j];
  }
}

// ---------------------------------------------------------------------------
// Kernel 2: fused g-MLP layers 2..4.
//  ROUND-9 = ROUND-8 + saddr weight addressing (last ~4-6 regs of spill).
//   Weights indexed as Base[woff + const] with 32-bit woff -> backend emits
//   global_load saddr form (SGPR base + 1 VGPR offset) instead of three
//   per-lane 64-bit pointer pairs. Demand drops below the 64-arch cap at
//   (512,4) -> spill-free (WRITE_SIZE is the check).
//   Structure unchanged: M=128 (2 i-objects), 512 thr / 8 waves, wave owns
//   128r x 32c, depth-2 b double-buffer, bias-in-acc-init, in-place 64 KB H,
//   BAR1 post-K-loop + BAR2 publish, grid 2048.
//  H layout: elem(row,c) = (c>>3)*1024 + ((row+(c>>3))&127)*8 + (c&7)
// ---------------------------------------------------------------------------
__device__ __forceinline__ int hidx128(int row, int c) {
  const int kb = c >> 3;
  return kb * 1024 + (((row + kb) & 127) << 3) + (c & 7);
}

template <bool LAST>
__device__ __forceinline__ void g_layer(__bf16* Hs,
                                        bf16x8 bb[2][2],
                                        const __bf16* __restrict__ Wcur,
                                        const __bf16* __restrict__ Wnext,
                                        int woff,
                                        const float* __restrict__ bias_g,
                                        int nq, int q, int r16,
                                        float* __restrict__ pr0,
                                        float* __restrict__ pr1) {
  f32x4 acc[8][2];
  {
    // bias folded into acc init (col bias constant over m); bv dead after this
    const f32x4 bv0 = *(const f32x4*)&bias_g[nq * 32 + 0 * 16 + q * 4];
    const f32x4 bv1 = *(const f32x4*)&bias_g[nq * 32 + 1 * 16 + q * 4];
#pragma unroll
    for (int m = 0; m < 8; ++m) {
      acc[m][0] = bv0;
      acc[m][1] = bv1;
    }
  }

#pragma unroll
  for (int ks = 0; ks < 8; ++ks) {
    const int kb = ks * 4 + q;
    const bf16x8 b0 = bb[ks & 1][0];
    const bf16x8 b1 = bb[ks & 1][1];
    // refill other slot: 1 K-step ahead; at ks=7 load next layer's ks=0
    // (slot parity consistent across layers since 8 is even)
    if (ks < 7) {
      bb[(ks + 1) & 1][0] = *(const bf16x8*)&Wcur[woff + (ks + 1) * 32];
      bb[(ks + 1) & 1][1] = *(const bf16x8*)&Wcur[woff + 4096 + (ks + 1) * 32];
    } else if (!LAST) {
      bb[0][0] = *(const bf16x8*)&Wnext[woff];
      bb[0][1] = *(const bf16x8*)&Wnext[woff + 4096];
    }
#pragma unroll
    for (int m = 0; m < 8; ++m) {
      const int row = m * 16 + r16;
      const bf16x8 a = *(const bf16x8*)(&Hs[kb * 1024 + (((row + kb) & 127) << 3)]);
      // swapped operands (verified): acc[m][nt] -> row m*16+r16,
      // cols nq*32 + nt*16 + q*4 + reg
      acc[m][0] = __builtin_amdgcn_mfma_f32_16x16x32_bf16(b0, a, acc[m][0], 0, 0, 0);
      acc[m][1] = __builtin_amdgcn_mfma_f32_16x16x32_bf16(b1, a, acc[m][1], 0, 0, 0);
    }
  }

  if (!LAST) {
    __syncthreads();   // BAR1: all waves finished reading Hs -> in-place safe
#pragma unroll
    for (int m = 0; m < 8; ++m)
#pragma unroll
      for (int nt = 0; nt < 2; ++nt) {
        const int cb = nq * 32 + nt * 16 + q * 4;
        bf16x4 h;
#pragma unroll
        for (int r = 0; r < 4; ++r) h[r] = (__bf16)fmaxf(acc[m][nt][r], 0.f);
        *(bf16x4*)(&Hs[hidx128(m * 16 + r16, cb)]) = h;
      }
    __syncthreads();   // BAR2: stores visible before next layer's reads
  } else {
    // j-sum for both i halves: rows 0-63 (m 0..3) -> i0, 64-127 (m 4..7) -> i1
#pragma unroll
    for (int h = 0; h < 2; ++h) {
#pragma unroll
      for (int nt = 0; nt < 2; ++nt) {
        const int cb = nq * 32 + nt * 16 + q * 4;
        f32x4 s;
#pragma unroll
        for (int r = 0; r < 4; ++r)
          s[r] = fmaxf(acc[h * 4 + 0][nt][r], 0.f)
               + fmaxf(acc[h * 4 + 1][nt][r], 0.f)
               + fmaxf(acc[h * 4 + 2][nt][r], 0.f)
               + fmaxf(acc[h * 4 + 3][nt][r], 0.f);
#pragma unroll
        for (int d = 1; d < 16; d <<= 1) {
#pragma unroll
          for (int r = 0; r < 4; ++r) s[r] += __shfl_xor(s[r], d, 64);
        }
        if (r16 == 0) *(f32x4*)&(h ? pr1 : pr0)[cb] = s;
      }
    }
  }
}

__global__ __launch_bounds__(512, 4) void rn_main(
    const float* __restrict__ U, const float* __restrict__ V,
    const float* __restrict__ Qb,
    const __bf16* __restrict__ W2t, const __bf16* __restrict__ W3t,
    const __bf16* __restrict__ W4t,
    const float* __restrict__ b2, const float* __restrict__ b3,
    const float* __restrict__ b4,
    float* __restrict__ part) {
  __shared__ __align__(16) __bf16 Hs[32768];   // 64 KB, in-place
  const int blk = blockIdx.x;
  const int nimg = blk >> 5, ipair = blk & 31;
  const int iobj0 = ipair * 2;
  const int t = threadIdx.x;
  const int nq = t >> 6, lane = t & 63;
  const int q = lane >> 4, r16 = lane & 15;

  // 32-bit weight offset (row = output col = nq*32 [+16] + r16, K off q*8);
  // uniform bases stay in SGPRs -> saddr-form loads, 1 VGPR of addressing
  const int woff = (nq * 32 + r16) * 256 + q * 8;

  // b double-buffer: preload layer-2 ks=0 (overlaps phase-0 loads/math)
  bf16x8 bb[2][2];
  bb[0][0] = *(const bf16x8*)&W2t[woff];
  bb[0][1] = *(const bf16x8*)&W2t[woff + 4096];

  // phase 0: rows 0-63 -> i0, rows 64-127 -> i1
  // h1[row][:] = relu(U[n, i(row), :] + V[n, j(row), :] + Qb[n, :])
  {
    const int c4 = t & 63;          // 4-float col group
    const int rb = t >> 6;          // 0..7 -> rows rb*16 .. rb*16+15
    const int isel = rb >> 2;       // 0 or 1 (static per thread)
    const f32x4 u4 = *(const f32x4*)&U[(size_t)(nimg * 64 + iobj0 + isel) * 256 + c4 * 4];
    const f32x4 q4 = *(const f32x4*)&Qb[(size_t)nimg * 256 + c4 * 4];
    const f32x4 uq = u4 + q4;
#pragma unroll
    for (int jj = 0; jj < 16; ++jj) {
      const int row = rb * 16 + jj;
      const int j = (rb & 3) * 16 + jj;
      const f32x4 v4 = *(const f32x4*)&V[(size_t)(nimg * 64 + j) * 256 + c4 * 4];
      bf16x4 h;
#pragma unroll
      for (int r = 0; r < 4; ++r) h[r] = (__bf16)fmaxf(uq[r] + v4[r], 0.f);
      *(bf16x4*)(&Hs[hidx128(row, c4 * 4)]) = h;
    }
  }
  __syncthreads();

  // part rows: global i-row index = nimg*64 + iobj0 (+1) = blk*2 (+1)
  float* pr0 = part + (size_t)blk * 512;
  float* pr1 = pr0 + 256;

  g_layer<false>(Hs, bb, W2t, W3t, woff, b2, nq, q, r16, pr0, pr1);
  g_layer<false>(Hs, bb, W3t, W4t, woff, b3, nq, q, r16, pr0, pr1);
  g_layer<true >(Hs, bb, W4t, W4t, woff, b4, nq, q, r16, pr0, pr1);
}

// ---------------------------------------------------------------------------
// Kernel 3: reduce partials -> context, f-MLP (fp32), log_softmax.
//  ROUND-9: 1024 threads (16 waves), split-K=4. Was 256 thr x 64 blocks =
//  1 wave/SIMD with three serial 256-iter GEMV chains -> fully exposed
//  latency. Now: group g = tid>>8 handles K-segment g*64..+64 (ctx: 16
//  i-rows each); partials combined in LDS. Serial chains ~4x shorter,
//  4 waves/SIMD of TLP.
// ---------------------------------------------------------------------------
__global__ __launch_bounds__(1024) void rn_final(
    const float* __restrict__ part,
    const float* __restrict__ f_w1, const float* __restrict__ f_b1,
    const float* __restrict__ f_w2, const float* __restrict__ f_b2,
    const float* __restrict__ f_w3, const float* __restrict__ f_b3,
    float* __restrict__ out) {
  __shared__ float red[4][256];
  __shared__ float ctx[256], y1[256], y2[256], sc[2];
  const int n = blockIdx.x;
  const int tid = threadIdx.x;
  const int o = tid & 255, g = tid >> 8;   // g in 0..3

  // ctx: each group sums 16 i-rows
  {
    float s = 0.f;
#pragma unroll 4
    for (int i = 0; i < 16; ++i)
      s += part[((size_t)n * 64 + g * 16 + i) * 256 + o];
    red[g][o] = s;
  }
  __syncthreads();
  if (g == 0)
    ctx[o] = (red[0][o] + red[1][o] + red[2][o] + red[3][o]) * (1.0f / 4096.0f);
  __syncthreads();

  // y1 = relu(ctx @ f_w1 + b1), split-K
  {
    float a = 0.f;
#pragma unroll 4
    for (int k = 0; k < 64; ++k)
      a += ctx[g * 64 + k] * f_w1[(g * 64 + k) * 256 + o];
    red[g][o] = a;
  }
  __syncthreads();
  if (g == 0)
    y1[o] = fmaxf(red[0][o] + red[1][o] + red[2][o] + red[3][o] + f_b1[o], 0.f);
  __syncthreads();

  // y2 = relu(y1 @ f_w2 + b2), split-K
  {
    float a = 0.f;
#pragma unroll 4
    for (int k = 0; k < 64; ++k)
      a += y1[g * 64 + k] * f_w2[(g * 64 + k) * 256 + o];
    red[g][o] = a;
  }
  __syncthreads();
  if (g == 0)
    y2[o] = fmaxf(red[0][o] + red[1][o] + red[2][o] + red[3][o] + f_b2[o], 0.f);
  __syncthreads();

  // scores + log_softmax
  if (tid < 2) {
    float c = f_b3[tid];
    for (int k = 0; k < 256; ++k) c += y2[k] * f_w3[k * 2 + tid];
    sc[tid] = c;
  }
  __syncthreads();
  if (tid == 0) {
    const float s0 = sc[0], s1 = sc[1];
    const float mx = fmaxf(s0, s1);
    const float lse = mx + logf(expf(s0 - mx) + expf(s1 - mx));
    out[n * 2 + 0] = s0 - lse;
    out[n * 2 + 1] = s1 - lse;
  }
}

// ---------------------------------------------------------------------------
extern "C" void kernel_launch(void* const* d_in, const int* in_sizes, int n_in,
                              void* d_out, int out_size, void* d_ws, size_t ws_size,
                              hipStream_t stream) {
  const float* img  = (const float*)d_in[0];
  const float* ques = (const float*)d_in[1];
  const float* g_w1 = (const float*)d_in[2];
  const float* g_b1 = (const float*)d_in[3];
  const float* g_w2 = (const float*)d_in[4];
  const float* g_b2 = (const float*)d_in[5];
  const float* g_w3 = (const float*)d_in[6];
  const float* g_b3 = (const float*)d_in[7];
  const float* g_w4 = (const float*)d_in[8];
  const float* g_b4 = (const float*)d_in[9];
  const float* f_w1 = (const float*)d_in[10];
  const float* f_b1 = (const float*)d_in[11];
  const float* f_w2 = (const float*)d_in[12];
  const float* f_b2 = (const float*)d_in[13];
  const float* f_w3 = (const float*)d_in[14];
  const float* f_b3 = (const float*)d_in[15];
  float* out = (float*)d_out;

  char* ws = (char*)d_ws;
  float*  U    = (float*)(ws);                                 // 4 MB
  float*  V    = (float*)(ws + (size_t)4  * 1048576);          // 4 MB
  float*  part = (float*)(ws + (size_t)8  * 1048576);          // 4 MB
  float*  Qb   = (float*)(ws + (size_t)12 * 1048576);          // 64 KB
  __bf16* W2t  = (__bf16*)(ws + (size_t)12 * 1048576 + 65536); // 128 KB each
  __bf16* W3t  = W2t + 65536;
  __bf16* W4t  = W3t + 65536;

  prep_kernel<<<624, 256, 0, stream>>>(img, ques, g_w1, g_b1, g_w2, g_w3, g_w4,
                                       U, V, Qb, W2t, W3t, W4t);
  rn_main<<<2048, 512, 0, stream>>>(U, V, Qb, W2t, W3t, W4t, g_b2, g_b3, g_b4, part);
  rn_final<<<64, 1024, 0, stream>>>(part, f_w1, f_b1, f_w2, f_b2, f_w3, f_b3, out);
}

// Round 12
// 224.140 us; speedup vs baseline: 1.6299x; 1.0199x over previous
//
#include <hip/hip_runtime.h>
#include <hip/hip_bf16.h>

typedef __bf16 bf16x8 __attribute__((ext_vector_type(8)));
typedef __bf16 bf16x4 __attribute__((ext_vector_type(4)));
typedef float  f32x4  __attribute__((ext_vector_type(4)));

// ---------------------------------------------------------------------------
// Kernel 1: prep (R9 form — validated)
// ---------------------------------------------------------------------------
__global__ __launch_bounds__(256) void prep_kernel(
    const float* __restrict__ img, const float* __restrict__ ques,
    const float* __restrict__ g_w1, const float* __restrict__ g_b1,
    const float* __restrict__ g_w2, const float* __restrict__ g_w3,
    const float* __restrict__ g_w4,
    float* __restrict__ U, float* __restrict__ V, float* __restrict__ Qb,
    __bf16* __restrict__ W2t, __bf16* __restrict__ W3t, __bf16* __restrict__ W4t) {
  __shared__ float smem[64 * 65];
  const int blk = blockIdx.x;
  const int t = threadIdx.x;

  if (blk < 512) {
    const int n = blk >> 3, obase = (blk & 7) * 8;
    for (int idx = t; idx < 66 * 8; idx += 256) {
      const int c = idx >> 3, o = obase + (idx & 7);
      float v;
      if (c < 64)      v = img[n * 4096 + c * 64 + o];
      else if (c == 64) v = (float)(o >> 3);
      else              v = (float)(o & 7);
      smem[idx] = v;
    }
    __syncthreads();
    float u[8], vv[8];
#pragma unroll
    for (int o = 0; o < 8; ++o) { u[o] = 0.f; vv[o] = 0.f; }
#pragma unroll 2
    for (int d = 0; d < 66; ++d) {
      const float wu = g_w1[d * 256 + t];
      const float wv = g_w1[(66 + d) * 256 + t];
#pragma unroll
      for (int o = 0; o < 8; ++o) {
        const float cc = smem[d * 8 + o];
        u[o]  += cc * wu;
        vv[o] += cc * wv;
      }
    }
#pragma unroll
    for (int o = 0; o < 8; ++o) {
      U[(size_t)(n * 64 + obase + o) * 256 + t] = u[o];
      V[(size_t)(n * 64 + obase + o) * 256 + t] = vv[o];
    }
  } else if (blk < 576) {
    const int n = blk - 512;
    smem[t] = ques[n * 256 + t];
    __syncthreads();
    float s = g_b1[t];
    for (int e = 0; e < 256; ++e) s += smem[e] * g_w1[(132 + e) * 256 + t];
    Qb[n * 256 + t] = s;
  } else {
    const int b2 = blk - 576;
    const int wsel = b2 >> 4;
    const int tile = b2 & 15;
    const int r0 = (tile >> 2) * 64, c0 = (tile & 3) * 64;
    const float* W = (wsel == 0) ? g_w2 : (wsel == 1) ? g_w3 : g_w4;
    __bf16* Wt    = (wsel == 0) ? W2t  : (wsel == 1) ? W3t  : W4t;
    const int col = t & 63, rb = (t >> 6) * 16;
#pragma unroll 4
    for (int j = 0; j < 16; ++j)
      smem[(rb + j) * 65 + col] = W[(size_t)(r0 + rb + j) * 256 + c0 + col];
    __syncthreads();
#pragma unroll 4
    for (int j = 0; j < 16; ++j)
      Wt[(size_t)(c0 + rb + j) * 256 + r0 + col] = (__bf16)smem[col * 65 + rb + j];
  }
}

// ---------------------------------------------------------------------------
// Kernel 2: fused g-MLP layers 2..4.
//  ROUND-11: FRAGMENT-NATIVE H LAYOUT.
//   Diagnosis: SQ_LDS_BANK_CONFLICT invariant (1.468e7) across all rotation
//   tweaks — a wave's A-read was 4 disjoint 256B regions (one per q-group),
//   aliasing 4-way across banks (~4.7 extra cyc per ds_read_b128). LDS pipe
//   = 61% of cycles, the binder.
//   FIX: store H in MFMA B-operand fragment order. Chunk (m-tile 0..7,
//   k-step 0..7): 64 lanes x 16B contiguous (canonical conflict-free read,
//   m134), stride 520 elems (+16B pad so phase-0 writes spread banks).
//     read  : Hs[(m*8+ks)*520 + lane*8]            (zero addr math in loop)
//     write : k = nq*32+nt*16+q*4+r -> chunk nq, q' = 2nt+(q>>1),
//             e = 4(q&1)+r  -> Hs[wb + m*4160 + nt*256], contiguous bf16x4
//     phase0: col = c4*4+r -> chunk c4>>3, q' = (c4>>1)&3, e = 4(c4&1)+r
//   Mapping verified against the operand-swapped 16x16x32 layouts
//   (B-op: slot = q*16 + j-row; C/D: row = out-col = q*4+reg, col = r16).
//   Rest identical to R8/R9: M=128, 512 thr / 8 waves, depth-2 bb,
//   bias-in-acc-init, in-place H, BAR1+BAR2, grid 2048, (512,4).
// ---------------------------------------------------------------------------
#define CH 520     // bf16 elems per chunk (512 data + 8 pad)

template <bool LAST>
__device__ __forceinline__ void g_layer(__bf16* Hs,
                                        bf16x8 bb[2][2],
                                        const __bf16* __restrict__ Wcur,
                                        const __bf16* __restrict__ Wnext,
                                        int woff, int lane8, int wb,
                                        const float* __restrict__ bias_g,
                                        int nq, int q, int r16,
                                        float* __restrict__ pr0,
                                        float* __restrict__ pr1) {
  f32x4 acc[8][2];
  {
    const f32x4 bv0 = *(const f32x4*)&bias_g[nq * 32 + 0 * 16 + q * 4];
    const f32x4 bv1 = *(const f32x4*)&bias_g[nq * 32 + 1 * 16 + q * 4];
#pragma unroll
    for (int m = 0; m < 8; ++m) {
      acc[m][0] = bv0;
      acc[m][1] = bv1;
    }
  }

#pragma unroll
  for (int ks = 0; ks < 8; ++ks) {
    const bf16x8 b0 = bb[ks & 1][0];
    const bf16x8 b1 = bb[ks & 1][1];
    // refill other slot: 1 K-step ahead; at ks=7 load next layer's ks=0
    if (ks < 7) {
      bb[(ks + 1) & 1][0] = *(const bf16x8*)&Wcur[woff + (ks + 1) * 32];
      bb[(ks + 1) & 1][1] = *(const bf16x8*)&Wcur[woff + 4096 + (ks + 1) * 32];
    } else if (!LAST) {
      bb[0][0] = *(const bf16x8*)&Wnext[woff];
      bb[0][1] = *(const bf16x8*)&Wnext[woff + 4096];
    }
#pragma unroll
    for (int m = 0; m < 8; ++m) {
      // contiguous 1KB wave read: chunk (m*8+ks), lane offset lane*8 elems
      const bf16x8 a = *(const bf16x8*)&Hs[(m * 8 + ks) * CH + lane8];
      // swapped operands (verified): acc[m][nt] -> row m*16+r16,
      // cols nq*32 + nt*16 + q*4 + reg
      acc[m][0] = __builtin_amdgcn_mfma_f32_16x16x32_bf16(b0, a, acc[m][0], 0, 0, 0);
      acc[m][1] = __builtin_amdgcn_mfma_f32_16x16x32_bf16(b1, a, acc[m][1], 0, 0, 0);
    }
  }

  if (!LAST) {
    __syncthreads();   // BAR1: all waves finished reading Hs -> in-place safe
#pragma unroll
    for (int m = 0; m < 8; ++m)
#pragma unroll
      for (int nt = 0; nt < 2; ++nt) {
        bf16x4 h;
#pragma unroll
        for (int r = 0; r < 4; ++r) h[r] = (__bf16)fmaxf(acc[m][nt][r], 0.f);
        // chunk nq, q' = 2nt+(q>>1), slot r16, e = 4(q&1)+r
        *(bf16x4*)&Hs[wb + m * (8 * CH) + nt * 256] = h;
      }
    __syncthreads();   // BAR2: stores visible before next layer's reads
  } else {
    // j-sum for both i halves: rows 0-63 (m 0..3) -> i0, 64-127 (m 4..7) -> i1
#pragma unroll
    for (int h = 0; h < 2; ++h) {
#pragma unroll
      for (int nt = 0; nt < 2; ++nt) {
        const int cb = nq * 32 + nt * 16 + q * 4;
        f32x4 s;
#pragma unroll
        for (int r = 0; r < 4; ++r)
          s[r] = fmaxf(acc[h * 4 + 0][nt][r], 0.f)
               + fmaxf(acc[h * 4 + 1][nt][r], 0.f)
               + fmaxf(acc[h * 4 + 2][nt][r], 0.f)
               + fmaxf(acc[h * 4 + 3][nt][r], 0.f);
#pragma unroll
        for (int d = 1; d < 16; d <<= 1) {
#pragma unroll
          for (int r = 0; r < 4; ++r) s[r] += __shfl_xor(s[r], d, 64);
        }
        if (r16 == 0) *(f32x4*)&(h ? pr1 : pr0)[cb] = s;
      }
    }
  }
}

__global__ __launch_bounds__(512, 4) void rn_main(
    const float* __restrict__ U, const float* __restrict__ V,
    const float* __restrict__ Qb,
    const __bf16* __restrict__ W2t, const __bf16* __restrict__ W3t,
    const __bf16* __restrict__ W4t,
    const float* __restrict__ b2, const float* __restrict__ b3,
    const float* __restrict__ b4,
    float* __restrict__ part) {
  __shared__ __align__(16) __bf16 Hs[64 * CH];   // 65 KB fragment-order H
  const int blk = blockIdx.x;
  const int nimg = blk >> 5, ipair = blk & 31;
  const int iobj0 = ipair * 2;
  const int t = threadIdx.x;
  const int nq = t >> 6, lane = t & 63;
  const int q = lane >> 4, r16 = lane & 15;

  // 32-bit weight offset (row = output col = nq*32 [+16] + r16, K off q*8)
  const int woff = (nq * 32 + r16) * 256 + q * 8;
  // LDS offsets: read = chunk base + lane8; write base wb (chunk nq)
  const int lane8 = lane * 8;
  const int wb = nq * CH + (q >> 1) * 128 + r16 * 8 + (q & 1) * 4;

  // b double-buffer: preload layer-2 ks=0 (overlaps phase-0 loads/math)
  bf16x8 bb[2][2];
  bb[0][0] = *(const bf16x8*)&W2t[woff];
  bb[0][1] = *(const bf16x8*)&W2t[woff + 4096];

  // phase 0: rows 0-63 -> i0, rows 64-127 -> i1
  // h1[row][:] = relu(U[n, i(row), :] + V[n, j(row), :] + Qb[n, :])
  {
    const int c4 = t & 63;          // 4-float col group (k = c4*4 .. +3)
    const int rb = t >> 6;          // m-tile 0..7 (rows rb*16 .. +15)
    const int isel = rb >> 2;       // 0 or 1 (static per thread)
    // fragment target: chunk rb*8 + (c4>>3), q' = (c4>>1)&3, e base 4*(c4&1)
    const int pb = (rb * 8 + (c4 >> 3)) * CH + ((c4 >> 1) & 3) * 128 + (c4 & 1) * 4;
    const f32x4 u4 = *(const f32x4*)&U[(size_t)(nimg * 64 + iobj0 + isel) * 256 + c4 * 4];
    const f32x4 q4 = *(const f32x4*)&Qb[(size_t)nimg * 256 + c4 * 4];
    const f32x4 uq = u4 + q4;
#pragma unroll
    for (int jj = 0; jj < 16; ++jj) {
      const int j = (rb & 3) * 16 + jj;
      const f32x4 v4 = *(const f32x4*)&V[(size_t)(nimg * 64 + j) * 256 + c4 * 4];
      bf16x4 h;
#pragma unroll
      for (int r = 0; r < 4; ++r) h[r] = (__bf16)fmaxf(uq[r] + v4[r], 0.f);
      *(bf16x4*)&Hs[pb + jj * 8] = h;   // slot jj within chunk
    }
  }
  __syncthreads();

  // part rows: global i-row index = nimg*64 + iobj0 (+1) = blk*2 (+1)
  float* pr0 = part + (size_t)blk * 512;
  float* pr1 = pr0 + 256;

  g_layer<false>(Hs, bb, W2t, W3t, woff, lane8, wb, b2, nq, q, r16, pr0, pr1);
  g_layer<false>(Hs, bb, W3t, W4t, woff, lane8, wb, b3, nq, q, r16, pr0, pr1);
  g_layer<true >(Hs, bb, W4t, W4t, woff, lane8, wb, b4, nq, q, r16, pr0, pr1);
}

// ---------------------------------------------------------------------------
// Kernel 3: reduce partials -> context, f-MLP (fp32), log_softmax.
// (R9 split-K form — validated)
// ---------------------------------------------------------------------------
__global__ __launch_bounds__(1024) void rn_final(
    const float* __restrict__ part,
    const float* __restrict__ f_w1, const float* __restrict__ f_b1,
    const float* __restrict__ f_w2, const float* __restrict__ f_b2,
    const float* __restrict__ f_w3, const float* __restrict__ f_b3,
    float* __restrict__ out) {
  __shared__ float red[4][256];
  __shared__ float ctx[256], y1[256], y2[256], sc[2];
  const int n = blockIdx.x;
  const int tid = threadIdx.x;
  const int o = tid & 255, g = tid >> 8;   // g in 0..3

  {
    float s = 0.f;
#pragma unroll 4
    for (int i = 0; i < 16; ++i)
      s += part[((size_t)n * 64 + g * 16 + i) * 256 + o];
    red[g][o] = s;
  }
  __syncthreads();
  if (g == 0)
    ctx[o] = (red[0][o] + red[1][o] + red[2][o] + red[3][o]) * (1.0f / 4096.0f);
  __syncthreads();

  {
    float a = 0.f;
#pragma unroll 4
    for (int k = 0; k < 64; ++k)
      a += ctx[g * 64 + k] * f_w1[(g * 64 + k) * 256 + o];
    red[g][o] = a;
  }
  __syncthreads();
  if (g == 0)
    y1[o] = fmaxf(red[0][o] + red[1][o] + red[2][o] + red[3][o] + f_b1[o], 0.f);
  __syncthreads();

  {
    float a = 0.f;
#pragma unroll 4
    for (int k = 0; k < 64; ++k)
      a += y1[g * 64 + k] * f_w2[(g * 64 + k) * 256 + o];
    red[g][o] = a;
  }
  __syncthreads();
  if (g == 0)
    y2[o] = fmaxf(red[0][o] + red[1][o] + red[2][o] + red[3][o] + f_b2[o], 0.f);
  __syncthreads();

  if (tid < 2) {
    float c = f_b3[tid];
    for (int k = 0; k < 256; ++k) c += y2[k] * f_w3[k * 2 + tid];
    sc[tid] = c;
  }
  __syncthreads();
  if (tid == 0) {
    const float s0 = sc[0], s1 = sc[1];
    const float mx = fmaxf(s0, s1);
    const float lse = mx + logf(expf(s0 - mx) + expf(s1 - mx));
    out[n * 2 + 0] = s0 - lse;
    out[n * 2 + 1] = s1 - lse;
  }
}

// ---------------------------------------------------------------------------
extern "C" void kernel_launch(void* const* d_in, const int* in_sizes, int n_in,
                              void* d_out, int out_size, void* d_ws, size_t ws_size,
                              hipStream_t stream) {
  const float* img  = (const float*)d_in[0];
  const float* ques = (const float*)d_in[1];
  const float* g_w1 = (const float*)d_in[2];
  const float* g_b1 = (const float*)d_in[3];
  const float* g_w2 = (const float*)d_in[4];
  const float* g_b2 = (const float*)d_in[5];
  const float* g_w3 = (const float*)d_in[6];
  const float* g_b3 = (const float*)d_in[7];
  const float* g_w4 = (const float*)d_in[8];
  const float* g_b4 = (const float*)d_in[9];
  const float* f_w1 = (const float*)d_in[10];
  const float* f_b1 = (const float*)d_in[11];
  const float* f_w2 = (const float*)d_in[12];
  const float* f_b2 = (const float*)d_in[13];
  const float* f_w3 = (const float*)d_in[14];
  const float* f_b3 = (const float*)d_in[15];
  float* out = (float*)d_out;

  char* ws = (char*)d_ws;
  float*  U    = (float*)(ws);                                 // 4 MB
  float*  V    = (float*)(ws + (size_t)4  * 1048576);          // 4 MB
  float*  part = (float*)(ws + (size_t)8  * 1048576);          // 4 MB
  float*  Qb   = (float*)(ws + (size_t)12 * 1048576);          // 64 KB
  __bf16* W2t  = (__bf16*)(ws + (size_t)12 * 1048576 + 65536); // 128 KB each
  __bf16* W3t  = W2t + 65536;
  __bf16* W4t  = W3t + 65536;

  prep_kernel<<<624, 256, 0, stream>>>(img, ques, g_w1, g_b1, g_w2, g_w3, g_w4,
                                       U, V, Qb, W2t, W3t, W4t);
  rn_main<<<2048, 512, 0, stream>>>(U, V, Qb, W2t, W3t, W4t, g_b2, g_b3, g_b4, part);
  rn_final<<<64, 1024, 0, stream>>>(part, f_w1, f_b1, f_w2, f_b2, f_w3, f_b3, out);
}